// Round 10
// baseline (267.786 us; speedup 1.0000x reference)
//
#include <hip/hip_runtime.h>

#define B_  4
#define L_  1024
#define D_  512
#define H_  8
#define DK_ 64
#define BL_ (B_*L_)

typedef unsigned short us16;   // raw bf16 bits
typedef __attribute__((ext_vector_type(8))) short bf16x8;
typedef __attribute__((ext_vector_type(4))) float f32x4;

__device__ __forceinline__ float us2f(us16 u) {
  union { unsigned int i; float f; } x;
  x.i = ((unsigned int)u) << 16;
  return x.f;
}
__device__ __forceinline__ us16 f2us(float f) {
  union { float f; unsigned int i; } x;
  x.f = f;
  unsigned int r = x.i + 0x7FFFu + ((x.i >> 16) & 1u);  // RNE
  return (us16)(r >> 16);
}

#define MFMA(a, b, c) __builtin_amdgcn_mfma_f32_16x16x32_bf16(a, b, c, 0, 0, 0)

// ---------------------------------------------------------------------------
// Fused weight transpose+cvt: 6 matrices, W f32 [k][n] -> bf16 [n][k].
// ---------------------------------------------------------------------------
struct WT6 {
  const float* src[6];
  us16* dst[6];
};
__global__ __launch_bounds__(256) void wtrans6(WT6 p) {
  __shared__ us16 T[64][72];
  const int z = blockIdx.z;
  const float* __restrict__ W = p.src[z];
  us16* __restrict__ Wt = p.dst[z];
  const int t = threadIdx.x;
  const int k0 = blockIdx.y * 64, n0 = blockIdx.x * 64;
  {
    int r = t >> 2, c = (t & 3) * 16;
    const float* src = W + (size_t)(k0 + r) * 512 + n0 + c;
    union { bf16x8 v; us16 u[8]; } p0, p1;
#pragma unroll
    for (int j = 0; j < 8; ++j) { p0.u[j] = f2us(src[j]); p1.u[j] = f2us(src[8 + j]); }
    *(bf16x8*)&T[r][c] = p0.v;
    *(bf16x8*)&T[r][c + 8] = p1.v;
  }
  __syncthreads();
  {
    int n = t >> 2, c = (t & 3) * 16;
    union { bf16x8 v; us16 u[8]; } p0, p1;
#pragma unroll
    for (int j = 0; j < 8; ++j) { p0.u[j] = T[c + j][n]; p1.u[j] = T[c + 8 + j][n]; }
    us16* dst = Wt + (size_t)(n0 + n) * 512 + k0 + c;
    *(bf16x8*)dst = p0.v;
    *(bf16x8*)(dst + 8) = p1.v;
  }
}

// g[row] = sigmoid(query[row,:] . gate_w + gate_b)
__global__ __launch_bounds__(256) void gate_kernel(
    const float* __restrict__ query, const float* __restrict__ gw,
    const float* __restrict__ gb, float* __restrict__ g) {
  int row = blockIdx.x * 4 + (threadIdx.x >> 6);
  int lane = threadIdx.x & 63;
  float p = 0.f;
  for (int d = lane; d < D_; d += 64) p += query[(size_t)row * D_ + d] * gw[d];
#pragma unroll
  for (int off = 32; off; off >>= 1) p += __shfl_down(p, off);
  if (lane == 0) g[row] = 1.f / (1.f + __expf(-(p + gb[0])));
}

// ---------------------------------------------------------------------------
// 128x128-tile GEMM (m93 ladder structure): 4 waves in 2x2, each owns 64x64
// (4x4 f32x4 acc). BK=32: 16 MFMA + 8 ds_read_b128 per wave per k-step.
// AMODE 0: A f32 (convert during staging); 1: A bf16.
// J.mode 0: C bf16 row-major; 1: C bf16 Vt [b][h][dk][kv]; 2: C f32.
// ---------------------------------------------------------------------------
struct GJob { const void* A; const us16* Wt; const float* bias; void* C; int mode; };
struct GJobs { GJob j[3]; };

template <int AMODE>
__global__ __launch_bounds__(256) void gemm128(GJobs jobs) {
  __shared__ us16 As[128][40];   // 80 B row stride (16B-multiple for b128)
  __shared__ us16 Ws[128][40];   // [n][k]
  const GJob J = jobs.j[blockIdx.z];
  const int tid = threadIdx.x;
  const int w = tid >> 6, lane = tid & 63;
  const int quad = lane >> 4, lc = lane & 15;
  const int wy = w >> 1, wx = w & 1;
  const int row0 = blockIdx.y * 128, col0 = blockIdx.x * 128;
  const int ar = tid >> 1, akc = (tid & 1) * 16;   // stage: 128 rows x 2 chunks
  f32x4 acc[4][4] = {};

  for (int k0 = 0; k0 < 512; k0 += 32) {
    if (AMODE == 0) {
      const float* as = (const float*)J.A + (size_t)(row0 + ar) * 512 + k0 + akc;
      union { bf16x8 v; us16 u[8]; } p0, p1;
#pragma unroll
      for (int j = 0; j < 8; ++j) { p0.u[j] = f2us(as[j]); p1.u[j] = f2us(as[8 + j]); }
      *(bf16x8*)&As[ar][akc] = p0.v;
      *(bf16x8*)&As[ar][akc + 8] = p1.v;
    } else {
      const us16* as = (const us16*)J.A + (size_t)(row0 + ar) * 512 + k0 + akc;
      *(bf16x8*)&As[ar][akc] = *(const bf16x8*)as;
      *(bf16x8*)&As[ar][akc + 8] = *(const bf16x8*)(as + 8);
    }
    {
      const us16* wsrc = J.Wt + (size_t)(col0 + ar) * 512 + k0 + akc;
      *(bf16x8*)&Ws[ar][akc] = *(const bf16x8*)wsrc;
      *(bf16x8*)&Ws[ar][akc + 8] = *(const bf16x8*)(wsrc + 8);
    }
    __syncthreads();
    bf16x8 af[4];
#pragma unroll
    for (int mt = 0; mt < 4; ++mt)
      af[mt] = *(const bf16x8*)&As[wy * 64 + mt * 16 + lc][quad * 8];
#pragma unroll
    for (int ct = 0; ct < 4; ++ct) {
      bf16x8 bf = *(const bf16x8*)&Ws[wx * 64 + ct * 16 + lc][quad * 8];
#pragma unroll
      for (int mt = 0; mt < 4; ++mt) acc[mt][ct] = MFMA(af[mt], bf, acc[mt][ct]);
    }
    __syncthreads();
  }

#pragma unroll
  for (int mt = 0; mt < 4; ++mt) {
    const int orow = row0 + wy * 64 + mt * 16 + quad * 4;
#pragma unroll
    for (int ct = 0; ct < 4; ++ct) {
      const int col = col0 + wx * 64 + ct * 16 + lc;
      const float bv = J.bias[col];
      if (J.mode == 0) {
        us16* C = (us16*)J.C;
#pragma unroll
        for (int r = 0; r < 4; ++r)
          C[(size_t)(orow + r) * 512 + col] = f2us(acc[mt][ct][r] + bv);
      } else if (J.mode == 1) {
        us16* C = (us16*)J.C;
        const int h = col >> 6, dk = col & 63;
#pragma unroll
        for (int r = 0; r < 4; ++r) {
          const int grow = orow + r;
          const int b = grow >> 10, kv = grow & 1023;
          C[(((size_t)b * H_ + h) * DK_ + dk) * L_ + kv] = f2us(acc[mt][ct][r] + bv);
        }
      } else {
        float* C = (float*)J.C;
#pragma unroll
        for (int r = 0; r < 4; ++r)
          C[(size_t)(orow + r) * 512 + col] = acc[mt][ct][r] + bv;
      }
    }
  }
}

// ---------------------------------------------------------------------------
// Mask 128x128 (NT): m = sigmoid(QP.KP^T / sqrt(512)) -> f32 out;
// Wk = g + (1-g)*exp(1-m) -> bf16 (head-independent calibration weight).
// ---------------------------------------------------------------------------
__global__ __launch_bounds__(256) void mask128(
    const us16* __restrict__ QP, const us16* __restrict__ KP,
    float* __restrict__ Mout, const float* __restrict__ gbuf,
    us16* __restrict__ Wk) {
  __shared__ us16 As[128][40];
  __shared__ us16 Bs[128][40];
  const int tid = threadIdx.x;
  const int w = tid >> 6, lane = tid & 63;
  const int quad = lane >> 4, lc = lane & 15;
  const int wy = w >> 1, wx = w & 1;
  const int b = blockIdx.z;
  const int row0 = blockIdx.y * 128, col0 = blockIdx.x * 128;
  const int ar = tid >> 1, akc = (tid & 1) * 16;
  const us16* Ab = QP + (size_t)b * L_ * D_;
  const us16* Bb = KP + (size_t)b * L_ * D_;
  f32x4 acc[4][4] = {};

  for (int k0 = 0; k0 < 512; k0 += 32) {
    {
      const us16* as = Ab + (size_t)(row0 + ar) * 512 + k0 + akc;
      *(bf16x8*)&As[ar][akc] = *(const bf16x8*)as;
      *(bf16x8*)&As[ar][akc + 8] = *(const bf16x8*)(as + 8);
      const us16* bs = Bb + (size_t)(col0 + ar) * 512 + k0 + akc;
      *(bf16x8*)&Bs[ar][akc] = *(const bf16x8*)bs;
      *(bf16x8*)&Bs[ar][akc + 8] = *(const bf16x8*)(bs + 8);
    }
    __syncthreads();
    bf16x8 af[4];
#pragma unroll
    for (int mt = 0; mt < 4; ++mt)
      af[mt] = *(const bf16x8*)&As[wy * 64 + mt * 16 + lc][quad * 8];
#pragma unroll
    for (int ct = 0; ct < 4; ++ct) {
      bf16x8 bf = *(const bf16x8*)&Bs[wx * 64 + ct * 16 + lc][quad * 8];
#pragma unroll
      for (int mt = 0; mt < 4; ++mt) acc[mt][ct] = MFMA(af[mt], bf, acc[mt][ct]);
    }
    __syncthreads();
  }

  const float sc = 0.04419417382415922f;  // 1/sqrt(512)
#pragma unroll
  for (int mt = 0; mt < 4; ++mt) {
    const int orow = row0 + wy * 64 + mt * 16 + quad * 4;
    float gq[4];
#pragma unroll
    for (int r = 0; r < 4; ++r) gq[r] = gbuf[b * L_ + orow + r];
#pragma unroll
    for (int ct = 0; ct < 4; ++ct) {
      const int col = col0 + wx * 64 + ct * 16 + lc;
#pragma unroll
      for (int r = 0; r < 4; ++r) {
        float x = acc[mt][ct][r] * sc;
        float v = 1.f / (1.f + __expf(-x));
        size_t idx = ((size_t)b * L_ + orow + r) * L_ + col;
        Mout[idx] = v;
        Wk[idx] = f2us(gq[r] + (1.f - gq[r]) * __expf(1.f - v));
      }
    }
  }
}

// ---------------------------------------------------------------------------
// Attention v3 (unchanged from round 9): scores in registers, fully unrolled;
// no max subtraction (logits sigma~0.2, comb <= e — exp args bounded, softmax
// shift-exact); wk precomputed bf16; 2 cross-wave reductions.
// O in place over Qp (blocks only touch their own cells).
// ---------------------------------------------------------------------------
__global__ __launch_bounds__(256, 4) void attn3(
    const us16* Qp, const us16* __restrict__ Kp,
    const us16* __restrict__ Vt, const us16* __restrict__ Wk, us16* O) {
  __shared__ us16 Ql[16][72];
  __shared__ us16 P[16 * 1032];
  __shared__ float red[2][4][16];
  const int tid = threadIdx.x;
  const int w = tid >> 6, lane = tid & 63;
  const int quad = lane >> 4, lc = lane & 15;
  const int b = blockIdx.z, h = blockIdx.y, q0 = blockIdx.x * 16;

  if (tid < 128) {
    int r = tid >> 3, ks = (tid & 7) * 8;
    *(bf16x8*)&Ql[r][ks] =
        *(const bf16x8*)(Qp + (size_t)(b * L_ + q0 + r) * D_ + h * DK_ + ks);
  }
  __syncthreads();

  bf16x8 qa0 = *(const bf16x8*)&Ql[lc][quad * 8];
  bf16x8 qa1 = *(const bf16x8*)&Ql[lc][32 + quad * 8];

  const us16* Kbase = Kp + (size_t)b * L_ * D_ + h * DK_;
  float s[16][4];
#pragma unroll
  for (int kt = 0; kt < 16; ++kt) {
    const us16* kr = Kbase + (size_t)(kt * 64 + w * 16 + lc) * D_;
    bf16x8 b0 = *(const bf16x8*)(kr + quad * 8);
    bf16x8 b1 = *(const bf16x8*)(kr + 32 + quad * 8);
    f32x4 a = {};
    a = MFMA(qa0, b0, a);
    a = MFMA(qa1, b1, a);
#pragma unroll
    for (int r = 0; r < 4; ++r) s[kt][r] = a[r] * 0.125f;
  }

  float sm[4];
#pragma unroll
  for (int r = 0; r < 4; ++r) {
    float t = 0.f;
#pragma unroll
    for (int kt = 0; kt < 16; ++kt) { s[kt][r] = __expf(s[kt][r]); t += s[kt][r]; }
#pragma unroll
    for (int off = 1; off < 16; off <<= 1) t += __shfl_xor(t, off);
    sm[r] = t;
  }
  if (lc == 0)
#pragma unroll
    for (int r = 0; r < 4; ++r) red[0][w][quad * 4 + r] = sm[r];
  __syncthreads();
  float inv[4];
#pragma unroll
  for (int r = 0; r < 4; ++r) {
    const int row = quad * 4 + r;
    inv[r] = 1.f / (red[0][0][row] + red[0][1][row] + red[0][2][row] + red[0][3][row]);
  }

#pragma unroll
  for (int r = 0; r < 4; ++r) {
    const us16* wkr =
        Wk + (size_t)(b * L_ + q0 + quad * 4 + r) * L_ + w * 16 + lc;
    float t = 0.f;
#pragma unroll
    for (int kt = 0; kt < 16; ++kt) {
      float c = s[kt][r] * inv[r] * us2f(wkr[kt * 64]);
      float e = __expf(c);
      s[kt][r] = e;
      t += e;
    }
#pragma unroll
    for (int off = 1; off < 16; off <<= 1) t += __shfl_xor(t, off);
    sm[r] = t;
  }
  if (lc == 0)
#pragma unroll
    for (int r = 0; r < 4; ++r) red[1][w][quad * 4 + r] = sm[r];
  __syncthreads();
#pragma unroll
  for (int r = 0; r < 4; ++r) {
    const int row = quad * 4 + r;
    inv[r] = 1.f / (red[1][0][row] + red[1][1][row] + red[1][2][row] + red[1][3][row]);
  }

#pragma unroll
  for (int kt = 0; kt < 16; ++kt)
#pragma unroll
    for (int r = 0; r < 4; ++r)
      P[(quad * 4 + r) * 1032 + kt * 64 + w * 16 + lc] = f2us(s[kt][r] * inv[r]);
  __syncthreads();

  const us16* Vb = Vt + (size_t)(b * H_ + h) * DK_ * L_;  // [dk][kv]
  f32x4 oacc = {};
  for (int kv = 0; kv < L_; kv += 32) {
    bf16x8 pa = *(const bf16x8*)&P[lc * 1032 + kv + quad * 8];
    bf16x8 vb = *(const bf16x8*)(Vb + (size_t)(w * 16 + lc) * L_ + kv + quad * 8);
    oacc = MFMA(pa, vb, oacc);
  }
#pragma unroll
  for (int r = 0; r < 4; ++r)
    O[(size_t)(b * L_ + q0 + quad * 4 + r) * D_ + h * DK_ + w * 16 + lc] =
        f2us(oacc[r]);
}

extern "C" void kernel_launch(void* const* d_in, const int* in_sizes, int n_in,
                              void* d_out, int out_size, void* d_ws, size_t ws_size,
                              hipStream_t stream) {
  const float* query   = (const float*)d_in[0];
  const float* key     = (const float*)d_in[1];
  const float* value   = (const float*)d_in[2];
  const float* wq_w    = (const float*)d_in[3];
  const float* wq_b    = (const float*)d_in[4];
  const float* wk_w    = (const float*)d_in[5];
  const float* wk_b    = (const float*)d_in[6];
  const float* wv_w    = (const float*)d_in[7];
  const float* wv_b    = (const float*)d_in[8];
  const float* dense_w = (const float*)d_in[9];
  const float* dense_b = (const float*)d_in[10];
  const float* gate_w  = (const float*)d_in[11];
  const float* gate_b  = (const float*)d_in[12];
  const float* mp_wq_w = (const float*)d_in[13];
  const float* mp_wq_b = (const float*)d_in[14];
  const float* mp_wk_w = (const float*)d_in[15];
  const float* mp_wk_b = (const float*)d_in[16];

  const size_t RSZ = (size_t)BL_ * D_;   // 2,097,152 elems
  const size_t WSZ = (size_t)D_ * D_;    // 262,144 elems
  us16* R0 = (us16*)d_ws;                // 4 MB  (QP, then Qp, then attn O)
  us16* R1 = R0 + RSZ;                   // 4 MB  (KP, then Kp)
  us16* Wt0 = R1 + RSZ;                  // 6 x 512 KB = 3 MB
  us16* mpq_t = Wt0;
  us16* mpk_t = Wt0 + WSZ;
  us16* wq_t  = Wt0 + 2 * WSZ;
  us16* wk_t  = Wt0 + 3 * WSZ;
  us16* wv_t  = Wt0 + 4 * WSZ;
  us16* dw_t  = Wt0 + 5 * WSZ;
  us16* Wk    = Wt0 + 6 * WSZ;           // 8 MB  (ws total 19 MB)

  float* out0 = (float*)d_out;                 // final out f32 (8 MB)
  float* outm = out0 + (size_t)B_ * L_ * D_;   // m f32 (16 MB)
  us16*  Vt   = (us16*)d_out;                  // V^T bf16 in out bytes [0,4M)
  float* gbuf = (float*)((char*)d_out + (4u << 20));

  dim3 blk(256);

  WT6 wt;
  wt.src[0] = mp_wq_w; wt.dst[0] = mpq_t;
  wt.src[1] = mp_wk_w; wt.dst[1] = mpk_t;
  wt.src[2] = wq_w;    wt.dst[2] = wq_t;
  wt.src[3] = wk_w;    wt.dst[3] = wk_t;
  wt.src[4] = wv_w;    wt.dst[4] = wv_t;
  wt.src[5] = dense_w; wt.dst[5] = dw_t;
  hipLaunchKernelGGL(wtrans6, dim3(8, 8, 6), blk, 0, stream, wt);
  hipLaunchKernelGGL(gate_kernel, dim3(BL_ / 4), blk, 0, stream, query, gate_w, gate_b, gbuf);

  // Mask-perturbation projections (f32 A): QP->R0, KP->R1.
  GJobs mp;
  mp.j[0] = { query, mpq_t, mp_wq_b, R0, 0 };
  mp.j[1] = { key,   mpk_t, mp_wk_b, R1, 0 };
  mp.j[2] = mp.j[1];
  hipLaunchKernelGGL(gemm128<0>, dim3(4, 32, 2), blk, 0, stream, mp);

  // Mask + calibration weight.
  hipLaunchKernelGGL(mask128, dim3(8, 8, 4), blk, 0, stream, R0, R1, outm, gbuf, Wk);

  // Q/K/V projections: Qp->R0, Kp->R1, V^T->Vt (d_out scratch).
  GJobs qkv;
  qkv.j[0] = { query, wq_t, wq_b, R0, 0 };
  qkv.j[1] = { key,   wk_t, wk_b, R1, 0 };
  qkv.j[2] = { value, wv_t, wv_b, Vt, 1 };
  hipLaunchKernelGGL(gemm128<0>, dim3(4, 32, 3), blk, 0, stream, qkv);

  // Attention (O in place over Qp/R0).
  hipLaunchKernelGGL(attn3, dim3(L_ / 16, H_, B_), blk, 0, stream, R0, R1, Vt, Wk, R0);

  // Final dense (bf16 A from ws, f32 out).
  GJobs dn;
  dn.j[0] = { R0, dw_t, dense_b, out0, 2 };
  dn.j[1] = dn.j[0];
  dn.j[2] = dn.j[0];
  hipLaunchKernelGGL(gemm128<1>, dim3(4, 32, 1), blk, 0, stream, dn);
}